// Round 1
// baseline (2660.780 us; speedup 1.0000x reference)
//
#include <hip/hip_runtime.h>
#include <cstdint>
#include <cstddef>

#define NVOX 300000
#define SB 4194304      // T*H*W = 2^22
#define ST 262144       // H*W   = 2^18
#define SHH 512         // W     = 2^9
#define SENT 33554432   // 2^25
#define NWORDS (SENT/64) // 524288 = 2^19

static __device__ __forceinline__ float bf2f(unsigned short u){
  return __uint_as_float(((unsigned)u) << 16);
}
static __device__ __forceinline__ unsigned short f2bf(float f){
  unsigned u = __float_as_uint(f);
  u = u + 0x7fffu + ((u >> 16) & 1u);
  return (unsigned short)(u >> 16);
}

// ---------------- mark: compute lin, set presence bit ----------------
__global__ void mark_kernel(const int* __restrict__ idx,
                            unsigned long long* __restrict__ bits,
                            int* __restrict__ lin){
  int i = blockIdx.x*256 + threadIdx.x;
  if(i >= NVOX) return;
  int4 v = ((const int4*)idx)[i];
  int l = v.x*SB + v.y*ST + v.z*SHH + v.w;
  lin[i] = l;
  atomicOr(&bits[l >> 6], 1ull << (l & 63));
}

// ---------------- scan of per-word popcounts ----------------
// scan1: each block scans 4096 words (256 thr x 16), coarse = block-local exclusive
__global__ void scan1_kernel(const unsigned long long* __restrict__ bits,
                             unsigned* __restrict__ coarse,
                             unsigned* __restrict__ blockSums){
  __shared__ unsigned sh[256];
  int t = threadIdx.x, blk = blockIdx.x;
  int w0 = blk*4096 + t*16;
  unsigned p[16]; unsigned s = 0;
  #pragma unroll
  for(int k=0;k<16;k++){ unsigned c = (unsigned)__popcll(bits[w0+k]); p[k] = s; s += c; }
  sh[t] = s; __syncthreads();
  for(int off=1; off<256; off<<=1){
    unsigned v = (t >= off) ? sh[t-off] : 0u;
    __syncthreads();
    sh[t] += v;
    __syncthreads();
  }
  unsigned texcl = (t == 0) ? 0u : sh[t-1];
  #pragma unroll
  for(int k=0;k<16;k++) coarse[w0+k] = texcl + p[k];
  if(t == 255) blockSums[blk] = sh[255];
}

// scan2: one block scans the 128 block sums -> blockExcl[0..128], blockExcl[128]=U
__global__ void scan2_kernel(const unsigned* __restrict__ blockSums,
                             unsigned* __restrict__ blockExcl){
  __shared__ unsigned sh[128];
  int t = threadIdx.x; // 128 threads
  sh[t] = blockSums[t]; __syncthreads();
  for(int off=1; off<128; off<<=1){
    unsigned v = (t >= off) ? sh[t-off] : 0u;
    __syncthreads();
    sh[t] += v;
    __syncthreads();
  }
  if(t == 0) blockExcl[0] = 0u;
  blockExcl[t+1] = sh[t];
}

// ---------------- emit comb_idx for real unique rows ----------------
__global__ void emit_kernel(const unsigned long long* __restrict__ bits,
                            const unsigned* __restrict__ coarse,
                            const unsigned* __restrict__ blockExcl,
                            float* __restrict__ out_comb){
  int w = blockIdx.x*256 + threadIdx.x;
  if(w >= NWORDS) return;
  unsigned long long bw = bits[w];
  if(!bw) return;
  unsigned j = coarse[w] + blockExcl[w >> 12];
  while(bw){
    int p = __builtin_ctzll(bw);
    bw &= bw - 1;
    int v = (w << 6) | p;
    int cb = v >> 22;
    int r  = v & (SB - 1);
    int ct = r >> 18;
    r &= (ST - 1);
    int ch = r >> 9;
    int cw = r & 511;
    ((float4*)out_comb)[j] = make_float4((float)cb,(float)ct,(float)ch,(float)cw);
    j++;
  }
}

// ---------------- fused 128x128 linear + LayerNorm (+ReLU / +mean partials) ----
// block = 256 thr, 64 rows/block. xs fp32 [64][132] (pad: conflict-free),
// W staged as bf16 in LDS (two 64-col halves). 4x4 register tiles, fp32 acc.
template<typename TIN, int RELU, int MEAN>
__global__ __launch_bounds__(256) void gemm_ln(const TIN* __restrict__ X,
    const float* __restrict__ W, const float* __restrict__ gamma,
    const float* __restrict__ beta, unsigned short* __restrict__ Y,
    float* __restrict__ sq, int nrows)
{
  __shared__ float xs[64][132];
  __shared__ unsigned short wsh[128][64];
  const int t = threadIdx.x;
  const int rowbase = blockIdx.x * 64;
  const int rg = t >> 4, cg = t & 15;
  const int r0 = rg * 4;

  float g_[8], be_[8];
  #pragma unroll
  for(int q=0;q<8;q++){
    int c = (q>>2)*64 + cg*4 + (q&3);
    g_[q] = gamma[c]; be_[q] = beta[c];
  }

  // stage X tile (64 rows x 128 cols)
  #pragma unroll
  for(int m=0;m<8;m++){
    int f = t + m*256;
    int row = f >> 5, c4 = f & 31;
    float4 v = make_float4(0.f,0.f,0.f,0.f);
    if(rowbase + row < nrows){
      if constexpr (sizeof(TIN) == 4){
        v = ((const float4*)X)[(size_t)(rowbase+row)*32 + c4];
      } else {
        ushort4 uv = ((const ushort4*)X)[(size_t)(rowbase+row)*32 + c4];
        v = make_float4(bf2f(uv.x), bf2f(uv.y), bf2f(uv.z), bf2f(uv.w));
      }
    }
    *(float4*)&xs[row][c4*4] = v;
  }

  float acc[4][8];
  #pragma unroll
  for(int i=0;i<4;i++)
    #pragma unroll
    for(int q=0;q<8;q++) acc[i][q] = 0.f;

  #pragma unroll
  for(int h=0;h<2;h++){
    __syncthreads();
    #pragma unroll
    for(int m=0;m<8;m++){
      int f = t + m*256;
      int k = f >> 4, c4 = f & 15;
      float4 wv = ((const float4*)W)[k*32 + h*16 + c4];
      ushort4 us;
      us.x = f2bf(wv.x); us.y = f2bf(wv.y); us.z = f2bf(wv.z); us.w = f2bf(wv.w);
      *(ushort4*)&wsh[k][c4*4] = us;
    }
    __syncthreads();
    for(int k=0;k<128;k+=4){
      float A[4][4];
      #pragma unroll
      for(int i=0;i<4;i++) *(float4*)&A[i][0] = *(const float4*)&xs[r0+i][k];
      #pragma unroll
      for(int kk=0;kk<4;kk++){
        ushort4 bw = *(const ushort4*)&wsh[k+kk][cg*4];
        float b0 = bf2f(bw.x), b1 = bf2f(bw.y), b2 = bf2f(bw.z), b3 = bf2f(bw.w);
        #pragma unroll
        for(int i=0;i<4;i++){
          acc[i][h*4+0] += A[i][kk]*b0;
          acc[i][h*4+1] += A[i][kk]*b1;
          acc[i][h*4+2] += A[i][kk]*b2;
          acc[i][h*4+3] += A[i][kk]*b3;
        }
      }
    }
  }

  float mv[8];
  #pragma unroll
  for(int q=0;q<8;q++) mv[q] = 0.f;

  #pragma unroll
  for(int i=0;i<4;i++){
    float rs = 0.f, rq = 0.f;
    #pragma unroll
    for(int q=0;q<8;q++){ float v = acc[i][q]; rs += v; rq += v*v; }
    #pragma unroll
    for(int m=1;m<16;m<<=1){ rs += __shfl_xor(rs, m); rq += __shfl_xor(rq, m); }
    float mu = rs * (1.f/128.f);
    float var = fmaxf(rq*(1.f/128.f) - mu*mu, 0.f);
    float rinv = rsqrtf(var + 1e-5f);
    int row = rowbase + r0 + i;
    bool rv = row < nrows;
    unsigned short us[8];
    #pragma unroll
    for(int q=0;q<8;q++){
      float v = (acc[i][q] - mu)*rinv*g_[q] + be_[q];
      if(RELU) v = fmaxf(v, 0.f);
      if(MEAN){ if(rv) mv[q] += v; }
      us[q] = f2bf(v);
    }
    if(rv){
      size_t e = (size_t)row*128 + cg*4;
      ushort4 o0; o0.x=us[0]; o0.y=us[1]; o0.z=us[2]; o0.w=us[3];
      *(ushort4*)(Y + e) = o0;
      ushort4 o1; o1.x=us[4]; o1.y=us[5]; o1.z=us[6]; o1.w=us[7];
      *(ushort4*)(Y + e + 64) = o1;
    }
  }

  if(MEAN){
    #pragma unroll
    for(int q=0;q<8;q++){
      float v = mv[q];
      v += __shfl_xor(v, 16); v += __shfl_xor(v, 32);
      if((t & 48) == 0){
        int c = (q>>2)*64 + cg*4 + (q&3);
        atomicAdd(&sq[c], v);
      }
    }
  }
}

// ---------------- SE: mean -> fc -> relu -> fc -> sigmoid ----------------
__global__ void se_kernel(const float* __restrict__ sq, const float* __restrict__ w1,
    const float* __restrict__ b1, const float* __restrict__ w2,
    const float* __restrict__ b2, float* __restrict__ scale)
{
  __shared__ float mean[128];
  __shared__ float h1[32];
  int t = threadIdx.x; // 128 threads
  mean[t] = sq[t] * (1.f/(float)NVOX);
  __syncthreads();
  if(t < 32){
    float s = b1[t];
    for(int c=0;c<128;c++) s += mean[c]*w1[c*32+t];
    h1[t] = fmaxf(s, 0.f);
  }
  __syncthreads();
  float s = b2[t];
  for(int j=0;j<32;j++) s += h1[j]*w2[j*128+t];
  scale[t] = 1.f/(1.f + expf(-s));
}

// ---------------- scatter: accum[rank(lin)] += y2*scale + feats ----------------
__global__ void scatter_kernel(const unsigned short* __restrict__ y2,
    const float* __restrict__ feats, const float* __restrict__ scale,
    const int* __restrict__ lin, const unsigned long long* __restrict__ bits,
    const unsigned* __restrict__ coarse, const unsigned* __restrict__ blockExcl,
    float* __restrict__ accum)
{
  int row = blockIdx.x*4 + (threadIdx.x >> 6);
  int lane = threadIdx.x & 63;
  int l = lin[row];
  int w = l >> 6;
  unsigned j = coarse[w] + blockExcl[w >> 12]
             + (unsigned)__popcll(bits[w] & ((1ull << (l & 63)) - 1ull));
  size_t rb = (size_t)row * 128;
  float v0 = bf2f(y2[rb + lane])      * scale[lane]      + feats[rb + lane];
  float v1 = bf2f(y2[rb + 64 + lane]) * scale[64 + lane] + feats[rb + 64 + lane];
  size_t ob = (size_t)j * 128;
  atomicAdd(accum + ob + lane, v0);
  atomicAdd(accum + ob + 64 + lane, v1);
}

// ---------------- finalize: valid mask + relu, pad rows ----------------
__global__ void finalize_kernel(float* __restrict__ accum,
    const unsigned* __restrict__ blockExcl, float* __restrict__ out_comb,
    float* __restrict__ out_valid)
{
  int row = blockIdx.x*4 + (threadIdx.x >> 6);
  int lane = threadIdx.x & 63;
  unsigned U = blockExcl[128];
  size_t rb = (size_t)row * 128;
  if((unsigned)row < U){
    float v0 = accum[rb + lane], v1 = accum[rb + 64 + lane];
    float s = fabsf(v0) + fabsf(v1);
    #pragma unroll
    for(int m=1;m<64;m<<=1) s += __shfl_xor(s, m);
    bool valid = s > 1e-8f;
    accum[rb + lane]      = valid ? fmaxf(v0, 0.f) : 0.f;
    accum[rb + 64 + lane] = valid ? fmaxf(v1, 0.f) : 0.f;
    if(lane == 0) out_valid[row] = valid ? 1.f : 0.f;
  } else {
    accum[rb + lane] = 0.f;
    accum[rb + 64 + lane] = 0.f;
    if(lane == 0) out_valid[row] = 0.f;
    if(lane < 4) out_comb[(size_t)row*4 + lane] = (lane == 0) ? 8.f : 0.f;
  }
}

extern "C" void kernel_launch(void* const* d_in, const int* in_sizes, int n_in,
                              void* d_out, int out_size, void* d_ws, size_t ws_size,
                              hipStream_t stream)
{
  const float* feats   = (const float*)d_in[0];
  const int*   indices = (const int*)d_in[1];
  const float* W1  = (const float*)d_in[2];
  const float* g1  = (const float*)d_in[3];
  const float* b1  = (const float*)d_in[4];
  const float* W2  = (const float*)d_in[5];
  const float* g2  = (const float*)d_in[6];
  const float* b2  = (const float*)d_in[7];
  const float* sw1 = (const float*)d_in[8];
  const float* sb1 = (const float*)d_in[9];
  const float* sw2 = (const float*)d_in[10];
  const float* sb2 = (const float*)d_in[11];

  float* out_merged = (float*)d_out;                        // [2N,128]
  float* out_comb   = out_merged + (size_t)2*NVOX*128;      // [2N,4]
  float* out_valid  = out_comb   + (size_t)2*NVOX*4;        // [2N]

  char* cur = (char*)d_ws;
  auto alloc = [&](size_t b) -> void* {
    void* p = (void*)cur;
    cur += (b + 255) & ~(size_t)255;
    return p;
  };
  unsigned short*      y1        = (unsigned short*)alloc((size_t)NVOX*128*2);
  unsigned short*      y2        = (unsigned short*)alloc((size_t)NVOX*128*2);
  unsigned long long*  bits      = (unsigned long long*)alloc((size_t)NWORDS*8);
  unsigned*            coarse    = (unsigned*)alloc((size_t)NWORDS*4);
  unsigned*            blockSums = (unsigned*)alloc(128*4);
  unsigned*            blockExcl = (unsigned*)alloc(129*4);
  float*               sq        = (float*)alloc(128*4);
  float*               scale     = (float*)alloc(128*4);
  int*                 lin       = (int*)alloc((size_t)NVOX*4);

  hipMemsetAsync(bits, 0, (size_t)NWORDS*8, stream);
  hipMemsetAsync(sq, 0, 128*4, stream);
  hipMemsetAsync(out_merged, 0, (size_t)NVOX*128*4, stream); // accum rows < U <= N

  mark_kernel<<<(NVOX+255)/256, 256, 0, stream>>>(indices, bits, lin);
  scan1_kernel<<<128, 256, 0, stream>>>(bits, coarse, blockSums);
  scan2_kernel<<<1, 128, 0, stream>>>(blockSums, blockExcl);
  emit_kernel<<<NWORDS/256, 256, 0, stream>>>(bits, coarse, blockExcl, out_comb);

  gemm_ln<float, 1, 0><<<(NVOX+63)/64, 256, 0, stream>>>(feats, W1, g1, b1, y1, sq, NVOX);
  gemm_ln<unsigned short, 0, 1><<<(NVOX+63)/64, 256, 0, stream>>>(y1, W2, g2, b2, y2, sq, NVOX);
  se_kernel<<<1, 128, 0, stream>>>(sq, sw1, sb1, sw2, sb2, scale);

  scatter_kernel<<<NVOX/4, 256, 0, stream>>>(y2, feats, scale, lin, bits, coarse, blockExcl, out_merged);
  finalize_kernel<<<(2*NVOX)/4, 256, 0, stream>>>(out_merged, blockExcl, out_comb, out_valid);
}

// Round 2
// 869.522 us; speedup vs baseline: 3.0600x; 3.0600x over previous
//
#include <hip/hip_runtime.h>
#include <cstdint>
#include <cstddef>

#define NVOX 300000
#define SB 4194304      // T*H*W = 2^22
#define ST 262144       // H*W   = 2^18
#define SHH 512         // W     = 2^9
#define SENT 33554432   // 2^25
#define NWORDS (SENT/64) // 524288 = 2^19

typedef __attribute__((ext_vector_type(8))) short short8;
typedef __attribute__((ext_vector_type(4))) float f32x4;

static __device__ __forceinline__ float bf2f(unsigned short u){
  return __uint_as_float(((unsigned)u) << 16);
}
static __device__ __forceinline__ unsigned short f2bf(float f){
  unsigned u = __float_as_uint(f);
  u = u + 0x7fffu + ((u >> 16) & 1u);
  return (unsigned short)(u >> 16);
}

// ---------------- pack W (fp32 KxN) -> Wt (bf16 NxK, transposed) ----------------
__global__ void pack_w(const float* __restrict__ W, unsigned short* __restrict__ Wt){
  int i = blockIdx.x*256 + threadIdx.x;  // 16384 elements
  int k = i >> 7, n = i & 127;
  Wt[n*128 + k] = f2bf(W[i]);
}

// ---------------- mark: compute lin, set presence bit ----------------
__global__ void mark_kernel(const int* __restrict__ idx,
                            unsigned long long* __restrict__ bits,
                            int* __restrict__ lin){
  int i = blockIdx.x*256 + threadIdx.x;
  if(i >= NVOX) return;
  int4 v = ((const int4*)idx)[i];
  int l = v.x*SB + v.y*ST + v.z*SHH + v.w;
  lin[i] = l;
  atomicOr(&bits[l >> 6], 1ull << (l & 63));
}

// ---------------- scan of per-word popcounts ----------------
__global__ void scan1_kernel(const unsigned long long* __restrict__ bits,
                             unsigned* __restrict__ coarse,
                             unsigned* __restrict__ blockSums){
  __shared__ unsigned sh[256];
  int t = threadIdx.x, blk = blockIdx.x;
  int w0 = blk*4096 + t*16;
  unsigned p[16]; unsigned s = 0;
  #pragma unroll
  for(int k=0;k<16;k++){ unsigned c = (unsigned)__popcll(bits[w0+k]); p[k] = s; s += c; }
  sh[t] = s; __syncthreads();
  for(int off=1; off<256; off<<=1){
    unsigned v = (t >= off) ? sh[t-off] : 0u;
    __syncthreads();
    sh[t] += v;
    __syncthreads();
  }
  unsigned texcl = (t == 0) ? 0u : sh[t-1];
  #pragma unroll
  for(int k=0;k<16;k++) coarse[w0+k] = texcl + p[k];
  if(t == 255) blockSums[blk] = sh[255];
}

__global__ void scan2_kernel(const unsigned* __restrict__ blockSums,
                             unsigned* __restrict__ blockExcl){
  __shared__ unsigned sh[128];
  int t = threadIdx.x; // 128 threads
  sh[t] = blockSums[t]; __syncthreads();
  for(int off=1; off<128; off<<=1){
    unsigned v = (t >= off) ? sh[t-off] : 0u;
    __syncthreads();
    sh[t] += v;
    __syncthreads();
  }
  if(t == 0) blockExcl[0] = 0u;
  blockExcl[t+1] = sh[t];
}

// ---------------- emit comb_idx for real unique rows ----------------
__global__ void emit_kernel(const unsigned long long* __restrict__ bits,
                            const unsigned* __restrict__ coarse,
                            const unsigned* __restrict__ blockExcl,
                            float* __restrict__ out_comb){
  int w = blockIdx.x*256 + threadIdx.x;
  if(w >= NWORDS) return;
  unsigned long long bw = bits[w];
  if(!bw) return;
  unsigned j = coarse[w] + blockExcl[w >> 12];
  while(bw){
    int p = __builtin_ctzll(bw);
    bw &= bw - 1;
    int v = (w << 6) | p;
    int cb = v >> 22;
    int r  = v & (SB - 1);
    int ct = r >> 18;
    r &= (ST - 1);
    int ch = r >> 9;
    int cw = r & 511;
    ((float4*)out_comb)[j] = make_float4((float)cb,(float)ct,(float)ch,(float)cw);
    j++;
  }
}

// ---------------- fused MLP: X @ W1 -> LN -> ReLU -> @ W2 -> LN, MFMA bf16 ------
// block = 256 thr = 4 waves; 64 rows/block, each wave owns 16 rows x 128 cols.
// A-frag: lane holds A[row=l15][k=quad*8+j]; B-frag from Wt (NxK bf16, global/L2).
// C/D layout: col=lane&15, row=quad*4+reg. LN via shfl_xor over low-4 lane bits.
__global__ __launch_bounds__(256) void fused_mlp(
    const float* __restrict__ X,
    const unsigned short* __restrict__ w1t, const float* __restrict__ g1v,
    const float* __restrict__ b1v,
    const unsigned short* __restrict__ w2t, const float* __restrict__ g2v,
    const float* __restrict__ b2v,
    unsigned short* __restrict__ Y, float* __restrict__ sq, int nrows)
{
  __shared__ __align__(16) unsigned short xs[64][136];  // stride 272B (17x16B)
  __shared__ float sqs[128];
  const int t = threadIdx.x;
  const int rowbase = blockIdx.x * 64;
  const int wave = t >> 6, quad = (t >> 4) & 3, l15 = t & 15;
  const int wbase = wave * 16;

  if (t < 128) sqs[t] = 0.f;

  // stage X (fp32 global) -> xs (bf16 LDS)
  #pragma unroll
  for (int m = 0; m < 8; m++) {
    int f4 = m*256 + t;             // 2048 float4 chunks = 64 rows x 32
    int row = f4 >> 5, c4 = f4 & 31;
    float4 v = make_float4(0.f,0.f,0.f,0.f);
    if (rowbase + row < nrows)
      v = ((const float4*)X)[(size_t)(rowbase+row)*32 + c4];
    ushort4 u;
    u.x = f2bf(v.x); u.y = f2bf(v.y); u.z = f2bf(v.z); u.w = f2bf(v.w);
    *(ushort4*)&xs[row][c4*4] = u;
  }
  __syncthreads();

  const int rowA = wbase + l15;
  const int kofs = quad * 8;

  // ================= GEMM1 + LN1 + ReLU =================
  {
    short8 a0 = *(const short8*)&xs[rowA][  0 + kofs];
    short8 a1 = *(const short8*)&xs[rowA][ 32 + kofs];
    short8 a2 = *(const short8*)&xs[rowA][ 64 + kofs];
    short8 a3 = *(const short8*)&xs[rowA][ 96 + kofs];

    f32x4 acc[8];
    #pragma unroll
    for (int nt = 0; nt < 8; nt++) {
      const unsigned short* wp = w1t + (size_t)(nt*16 + l15)*128 + kofs;
      short8 bv0 = *(const short8*)(wp);
      short8 bv1 = *(const short8*)(wp + 32);
      short8 bv2 = *(const short8*)(wp + 64);
      short8 bv3 = *(const short8*)(wp + 96);
      f32x4 c = {0.f,0.f,0.f,0.f};
      c = __builtin_amdgcn_mfma_f32_16x16x32_bf16(a0, bv0, c, 0, 0, 0);
      c = __builtin_amdgcn_mfma_f32_16x16x32_bf16(a1, bv1, c, 0, 0, 0);
      c = __builtin_amdgcn_mfma_f32_16x16x32_bf16(a2, bv2, c, 0, 0, 0);
      c = __builtin_amdgcn_mfma_f32_16x16x32_bf16(a3, bv3, c, 0, 0, 0);
      acc[nt] = c;
    }

    float gg[8], bb[8];
    #pragma unroll
    for (int nt = 0; nt < 8; nt++) {
      gg[nt] = g1v[nt*16 + l15]; bb[nt] = b1v[nt*16 + l15];
    }
    #pragma unroll
    for (int r = 0; r < 4; r++) {
      float s = 0.f, q = 0.f;
      #pragma unroll
      for (int nt = 0; nt < 8; nt++) { float v = acc[nt][r]; s += v; q += v*v; }
      #pragma unroll
      for (int m = 1; m < 16; m <<= 1) { s += __shfl_xor(s, m); q += __shfl_xor(q, m); }
      float mu = s * (1.f/128.f);
      float var = fmaxf(q * (1.f/128.f) - mu*mu, 0.f);
      float rinv = rsqrtf(var + 1e-5f);
      int orow = wbase + quad*4 + r;
      #pragma unroll
      for (int nt = 0; nt < 8; nt++) {
        float v = (acc[nt][r] - mu) * rinv * gg[nt] + bb[nt];
        v = fmaxf(v, 0.f);
        xs[orow][nt*16 + l15] = f2bf(v);   // wave-private rows: no barrier
      }
    }
  }

  // ================= GEMM2 + LN2 + SE partial sums =================
  {
    short8 a0 = *(const short8*)&xs[rowA][  0 + kofs];
    short8 a1 = *(const short8*)&xs[rowA][ 32 + kofs];
    short8 a2 = *(const short8*)&xs[rowA][ 64 + kofs];
    short8 a3 = *(const short8*)&xs[rowA][ 96 + kofs];

    f32x4 acc[8];
    #pragma unroll
    for (int nt = 0; nt < 8; nt++) {
      const unsigned short* wp = w2t + (size_t)(nt*16 + l15)*128 + kofs;
      short8 bv0 = *(const short8*)(wp);
      short8 bv1 = *(const short8*)(wp + 32);
      short8 bv2 = *(const short8*)(wp + 64);
      short8 bv3 = *(const short8*)(wp + 96);
      f32x4 c = {0.f,0.f,0.f,0.f};
      c = __builtin_amdgcn_mfma_f32_16x16x32_bf16(a0, bv0, c, 0, 0, 0);
      c = __builtin_amdgcn_mfma_f32_16x16x32_bf16(a1, bv1, c, 0, 0, 0);
      c = __builtin_amdgcn_mfma_f32_16x16x32_bf16(a2, bv2, c, 0, 0, 0);
      c = __builtin_amdgcn_mfma_f32_16x16x32_bf16(a3, bv3, c, 0, 0, 0);
      acc[nt] = c;
    }

    float gg[8], bb[8], ch[8];
    #pragma unroll
    for (int nt = 0; nt < 8; nt++) {
      gg[nt] = g2v[nt*16 + l15]; bb[nt] = b2v[nt*16 + l15]; ch[nt] = 0.f;
    }
    #pragma unroll
    for (int r = 0; r < 4; r++) {
      float s = 0.f, q = 0.f;
      #pragma unroll
      for (int nt = 0; nt < 8; nt++) { float v = acc[nt][r]; s += v; q += v*v; }
      #pragma unroll
      for (int m = 1; m < 16; m <<= 1) { s += __shfl_xor(s, m); q += __shfl_xor(q, m); }
      float mu = s * (1.f/128.f);
      float var = fmaxf(q * (1.f/128.f) - mu*mu, 0.f);
      float rinv = rsqrtf(var + 1e-5f);
      int orow = wbase + quad*4 + r;
      bool rv = (rowbase + orow) < nrows;
      #pragma unroll
      for (int nt = 0; nt < 8; nt++) {
        float v = (acc[nt][r] - mu) * rinv * gg[nt] + bb[nt];
        if (rv) ch[nt] += v;
        xs[orow][nt*16 + l15] = f2bf(v);
      }
    }
    // SE channel partials: reduce across quads, then LDS atomics
    #pragma unroll
    for (int nt = 0; nt < 8; nt++) {
      float v = ch[nt];
      v += __shfl_xor(v, 16); v += __shfl_xor(v, 32);
      if (quad == 0) atomicAdd(&sqs[nt*16 + l15], v);
    }
  }

  __syncthreads();
  // vector store y2: bf16, fully coalesced ushort8
  #pragma unroll
  for (int m = 0; m < 4; m++) {
    int c = m*256 + t;              // 1024 chunks of 8 shorts
    int row = c >> 4, s8 = c & 15;
    if (rowbase + row < nrows) {
      short8 v = *(const short8*)&xs[row][s8*8];
      *(short8*)(Y + (size_t)(rowbase+row)*128 + s8*8) = v;
    }
  }
  if (t < 128) atomicAdd(&sq[t], sqs[t]);
}

// ---------------- SE: mean -> fc -> relu -> fc -> sigmoid ----------------
__global__ void se_kernel(const float* __restrict__ sq, const float* __restrict__ w1,
    const float* __restrict__ b1, const float* __restrict__ w2,
    const float* __restrict__ b2, float* __restrict__ scale)
{
  __shared__ float mean[128];
  __shared__ float h1[32];
  int t = threadIdx.x; // 128 threads
  mean[t] = sq[t] * (1.f/(float)NVOX);
  __syncthreads();
  if(t < 32){
    float s = b1[t];
    for(int c=0;c<128;c++) s += mean[c]*w1[c*32+t];
    h1[t] = fmaxf(s, 0.f);
  }
  __syncthreads();
  float s = b2[t];
  for(int j=0;j<32;j++) s += h1[j]*w2[j*128+t];
  scale[t] = 1.f/(1.f + expf(-s));
}

// ---------------- scatter: accum[rank(lin)] += y2*scale + feats ----------------
__global__ void scatter_kernel(const unsigned short* __restrict__ y2,
    const float* __restrict__ feats, const float* __restrict__ scale,
    const int* __restrict__ lin, const unsigned long long* __restrict__ bits,
    const unsigned* __restrict__ coarse, const unsigned* __restrict__ blockExcl,
    float* __restrict__ accum)
{
  int row = blockIdx.x*4 + (threadIdx.x >> 6);
  int lane = threadIdx.x & 63;
  int l = lin[row];
  int w = l >> 6;
  unsigned j = coarse[w] + blockExcl[w >> 12]
             + (unsigned)__popcll(bits[w] & ((1ull << (l & 63)) - 1ull));
  size_t rb = (size_t)row * 128;
  float v0 = bf2f(y2[rb + lane])      * scale[lane]      + feats[rb + lane];
  float v1 = bf2f(y2[rb + 64 + lane]) * scale[64 + lane] + feats[rb + 64 + lane];
  size_t ob = (size_t)j * 128;
  atomicAdd(accum + ob + lane, v0);
  atomicAdd(accum + ob + 64 + lane, v1);
}

// ---------------- finalize: valid mask + relu, pad rows ----------------
__global__ void finalize_kernel(float* __restrict__ accum,
    const unsigned* __restrict__ blockExcl, float* __restrict__ out_comb,
    float* __restrict__ out_valid)
{
  int row = blockIdx.x*4 + (threadIdx.x >> 6);
  int lane = threadIdx.x & 63;
  unsigned U = blockExcl[128];
  size_t rb = (size_t)row * 128;
  if((unsigned)row < U){
    float v0 = accum[rb + lane], v1 = accum[rb + 64 + lane];
    float s = fabsf(v0) + fabsf(v1);
    #pragma unroll
    for(int m=1;m<64;m<<=1) s += __shfl_xor(s, m);
    bool valid = s > 1e-8f;
    accum[rb + lane]      = valid ? fmaxf(v0, 0.f) : 0.f;
    accum[rb + 64 + lane] = valid ? fmaxf(v1, 0.f) : 0.f;
    if(lane == 0) out_valid[row] = valid ? 1.f : 0.f;
  } else {
    accum[rb + lane] = 0.f;
    accum[rb + 64 + lane] = 0.f;
    if(lane == 0) out_valid[row] = 0.f;
    if(lane < 4) out_comb[(size_t)row*4 + lane] = (lane == 0) ? 8.f : 0.f;
  }
}

extern "C" void kernel_launch(void* const* d_in, const int* in_sizes, int n_in,
                              void* d_out, int out_size, void* d_ws, size_t ws_size,
                              hipStream_t stream)
{
  const float* feats   = (const float*)d_in[0];
  const int*   indices = (const int*)d_in[1];
  const float* W1  = (const float*)d_in[2];
  const float* g1  = (const float*)d_in[3];
  const float* b1  = (const float*)d_in[4];
  const float* W2  = (const float*)d_in[5];
  const float* g2  = (const float*)d_in[6];
  const float* b2  = (const float*)d_in[7];
  const float* sw1 = (const float*)d_in[8];
  const float* sb1 = (const float*)d_in[9];
  const float* sw2 = (const float*)d_in[10];
  const float* sb2 = (const float*)d_in[11];

  float* out_merged = (float*)d_out;                        // [2N,128]
  float* out_comb   = out_merged + (size_t)2*NVOX*128;      // [2N,4]
  float* out_valid  = out_comb   + (size_t)2*NVOX*4;        // [2N]

  char* cur = (char*)d_ws;
  auto alloc = [&](size_t b) -> void* {
    void* p = (void*)cur;
    cur += (b + 255) & ~(size_t)255;
    return p;
  };
  unsigned short*      y2        = (unsigned short*)alloc((size_t)NVOX*128*2);
  unsigned long long*  bits      = (unsigned long long*)alloc((size_t)NWORDS*8);
  unsigned*            coarse    = (unsigned*)alloc((size_t)NWORDS*4);
  unsigned*            blockSums = (unsigned*)alloc(128*4);
  unsigned*            blockExcl = (unsigned*)alloc(129*4);
  float*               sq        = (float*)alloc(128*4);
  float*               scale     = (float*)alloc(128*4);
  int*                 lin       = (int*)alloc((size_t)NVOX*4);
  unsigned short*      w1t       = (unsigned short*)alloc(128*128*2);
  unsigned short*      w2t       = (unsigned short*)alloc(128*128*2);

  hipMemsetAsync(bits, 0, (size_t)NWORDS*8, stream);
  hipMemsetAsync(sq, 0, 128*4, stream);
  hipMemsetAsync(out_merged, 0, (size_t)NVOX*128*4, stream); // accum rows < U <= N

  pack_w<<<64, 256, 0, stream>>>(W1, w1t);
  pack_w<<<64, 256, 0, stream>>>(W2, w2t);

  mark_kernel<<<(NVOX+255)/256, 256, 0, stream>>>(indices, bits, lin);
  scan1_kernel<<<128, 256, 0, stream>>>(bits, coarse, blockSums);
  scan2_kernel<<<1, 128, 0, stream>>>(blockSums, blockExcl);
  emit_kernel<<<NWORDS/256, 256, 0, stream>>>(bits, coarse, blockExcl, out_comb);

  fused_mlp<<<(NVOX+63)/64, 256, 0, stream>>>(feats, w1t, g1, b1, w2t, g2, b2,
                                              y2, sq, NVOX);
  se_kernel<<<1, 128, 0, stream>>>(sq, sw1, sb1, sw2, sb2, scale);

  scatter_kernel<<<NVOX/4, 256, 0, stream>>>(y2, feats, scale, lin, bits, coarse, blockExcl, out_merged);
  finalize_kernel<<<(2*NVOX)/4, 256, 0, stream>>>(out_merged, blockExcl, out_comb, out_valid);
}

// Round 3
// 800.430 us; speedup vs baseline: 3.3242x; 1.0863x over previous
//
#include <hip/hip_runtime.h>
#include <cstdint>
#include <cstddef>

#define NVOX 300000
#define SB 4194304      // T*H*W = 2^22
#define ST 262144       // H*W   = 2^18
#define SHH 512         // W     = 2^9
#define SENT 33554432   // 2^25
#define NWORDS (SENT/64) // 524288 = 2^19

typedef __attribute__((ext_vector_type(8))) short short8;
typedef __attribute__((ext_vector_type(4))) float f32x4;

static __device__ __forceinline__ float bf2f(unsigned short u){
  return __uint_as_float(((unsigned)u) << 16);
}
static __device__ __forceinline__ unsigned short f2bf(float f){
  unsigned u = __float_as_uint(f);
  u = u + 0x7fffu + ((u >> 16) & 1u);
  return (unsigned short)(u >> 16);
}

// ---- pack W (fp32 KxN) -> fragment-contiguous bf16 layout ----
// Element for (nt, ks, lane, j) at ((nt*4+ks)*64 + lane)*8 + j, holding
// W[k=ks*32+(lane>>4)*8+j][n=nt*16+(lane&15)]. A wave's B-frag load is then
// lane L reading 16B at byte offset 16*L of a contiguous 1KB block.
__global__ void pack_w(const float* __restrict__ W, unsigned short* __restrict__ Wt){
  int i = blockIdx.x*256 + threadIdx.x;  // 16384 elements
  int j = i & 7, lane = (i >> 3) & 63, ks = (i >> 9) & 3, nt = i >> 11;
  int k = ks*32 + (lane >> 4)*8 + j;
  int n = nt*16 + (lane & 15);
  Wt[i] = f2bf(W[k*128 + n]);
}

// ---------------- mark: compute lin, set presence bit ----------------
__global__ void mark_kernel(const int* __restrict__ idx,
                            unsigned long long* __restrict__ bits,
                            int* __restrict__ lin){
  int i = blockIdx.x*256 + threadIdx.x;
  if(i >= NVOX) return;
  int4 v = ((const int4*)idx)[i];
  int l = v.x*SB + v.y*ST + v.z*SHH + v.w;
  lin[i] = l;
  atomicOr(&bits[l >> 6], 1ull << (l & 63));
}

// ---------------- scan of per-word popcounts ----------------
__global__ void scan1_kernel(const unsigned long long* __restrict__ bits,
                             unsigned* __restrict__ coarse,
                             unsigned* __restrict__ blockSums){
  __shared__ unsigned sh[256];
  int t = threadIdx.x, blk = blockIdx.x;
  int w0 = blk*4096 + t*16;
  unsigned p[16]; unsigned s = 0;
  #pragma unroll
  for(int k=0;k<16;k++){ unsigned c = (unsigned)__popcll(bits[w0+k]); p[k] = s; s += c; }
  sh[t] = s; __syncthreads();
  for(int off=1; off<256; off<<=1){
    unsigned v = (t >= off) ? sh[t-off] : 0u;
    __syncthreads();
    sh[t] += v;
    __syncthreads();
  }
  unsigned texcl = (t == 0) ? 0u : sh[t-1];
  #pragma unroll
  for(int k=0;k<16;k++) coarse[w0+k] = texcl + p[k];
  if(t == 255) blockSums[blk] = sh[255];
}

__global__ void scan2_kernel(const unsigned* __restrict__ blockSums,
                             unsigned* __restrict__ blockExcl){
  __shared__ unsigned sh[128];
  int t = threadIdx.x; // 128 threads
  sh[t] = blockSums[t]; __syncthreads();
  for(int off=1; off<128; off<<=1){
    unsigned v = (t >= off) ? sh[t-off] : 0u;
    __syncthreads();
    sh[t] += v;
    __syncthreads();
  }
  if(t == 0) blockExcl[0] = 0u;
  blockExcl[t+1] = sh[t];
}

// ---------------- emit comb_idx for real unique rows ----------------
__global__ void emit_kernel(const unsigned long long* __restrict__ bits,
                            const unsigned* __restrict__ coarse,
                            const unsigned* __restrict__ blockExcl,
                            float* __restrict__ out_comb){
  int w = blockIdx.x*256 + threadIdx.x;
  if(w >= NWORDS) return;
  unsigned long long bw = bits[w];
  if(!bw) return;
  unsigned j = coarse[w] + blockExcl[w >> 12];
  while(bw){
    int p = __builtin_ctzll(bw);
    bw &= bw - 1;
    int v = (w << 6) | p;
    int cb = v >> 22;
    int r  = v & (SB - 1);
    int ct = r >> 18;
    r &= (ST - 1);
    int ch = r >> 9;
    int cw = r & 511;
    ((float4*)out_comb)[j] = make_float4((float)cb,(float)ct,(float)ch,(float)cw);
    j++;
  }
}

// ---------------- fused MLP: X @ W1 -> LN -> ReLU -> @ W2 -> LN, MFMA bf16 ------
// block = 256 thr = 4 waves; 64 rows/block, each wave owns 16 rows x 128 cols.
// B-frags come from fragment-contiguous Wt: one coalesced 1KB load per wave,
// identical across waves (L1 broadcast).
__global__ __launch_bounds__(256) void fused_mlp(
    const float* __restrict__ X,
    const unsigned short* __restrict__ w1t, const float* __restrict__ g1v,
    const float* __restrict__ b1v,
    const unsigned short* __restrict__ w2t, const float* __restrict__ g2v,
    const float* __restrict__ b2v,
    unsigned short* __restrict__ Y, float* __restrict__ sq, int nrows)
{
  __shared__ __align__(16) unsigned short xs[64][136];  // stride 272B
  __shared__ float sqs[128];
  const int t = threadIdx.x;
  const int rowbase = blockIdx.x * 64;
  const int wave = t >> 6, quad = (t >> 4) & 3, l15 = t & 15;
  const int wbase = wave * 16;
  const int lane8 = (t & 63) * 8;   // byte/short offset of this lane's frag

  if (t < 128) sqs[t] = 0.f;

  // stage X (fp32 global) -> xs (bf16 LDS)
  #pragma unroll
  for (int m = 0; m < 8; m++) {
    int f4 = m*256 + t;             // 2048 float4 chunks = 64 rows x 32
    int row = f4 >> 5, c4 = f4 & 31;
    float4 v = make_float4(0.f,0.f,0.f,0.f);
    if (rowbase + row < nrows)
      v = ((const float4*)X)[(size_t)(rowbase+row)*32 + c4];
    ushort4 u;
    u.x = f2bf(v.x); u.y = f2bf(v.y); u.z = f2bf(v.z); u.w = f2bf(v.w);
    *(ushort4*)&xs[row][c4*4] = u;
  }
  __syncthreads();

  const int rowA = wbase + l15;
  const int kofs = quad * 8;

  // ================= GEMM1 + LN1 + ReLU =================
  {
    short8 a0 = *(const short8*)&xs[rowA][  0 + kofs];
    short8 a1 = *(const short8*)&xs[rowA][ 32 + kofs];
    short8 a2 = *(const short8*)&xs[rowA][ 64 + kofs];
    short8 a3 = *(const short8*)&xs[rowA][ 96 + kofs];

    f32x4 acc[8];
    #pragma unroll
    for (int nt = 0; nt < 8; nt++) {
      const unsigned short* wp = w1t + nt*2048 + lane8;
      short8 bv0 = *(const short8*)(wp);
      short8 bv1 = *(const short8*)(wp + 512);
      short8 bv2 = *(const short8*)(wp + 1024);
      short8 bv3 = *(const short8*)(wp + 1536);
      f32x4 c = {0.f,0.f,0.f,0.f};
      c = __builtin_amdgcn_mfma_f32_16x16x32_bf16(a0, bv0, c, 0, 0, 0);
      c = __builtin_amdgcn_mfma_f32_16x16x32_bf16(a1, bv1, c, 0, 0, 0);
      c = __builtin_amdgcn_mfma_f32_16x16x32_bf16(a2, bv2, c, 0, 0, 0);
      c = __builtin_amdgcn_mfma_f32_16x16x32_bf16(a3, bv3, c, 0, 0, 0);
      acc[nt] = c;
    }

    float gg[8], bb[8];
    #pragma unroll
    for (int nt = 0; nt < 8; nt++) {
      gg[nt] = g1v[nt*16 + l15]; bb[nt] = b1v[nt*16 + l15];
    }
    #pragma unroll
    for (int r = 0; r < 4; r++) {
      float s = 0.f, q = 0.f;
      #pragma unroll
      for (int nt = 0; nt < 8; nt++) { float v = acc[nt][r]; s += v; q += v*v; }
      #pragma unroll
      for (int m = 1; m < 16; m <<= 1) { s += __shfl_xor(s, m); q += __shfl_xor(q, m); }
      float mu = s * (1.f/128.f);
      float var = fmaxf(q * (1.f/128.f) - mu*mu, 0.f);
      float rinv = rsqrtf(var + 1e-5f);
      int orow = wbase + quad*4 + r;
      #pragma unroll
      for (int nt = 0; nt < 8; nt++) {
        float v = (acc[nt][r] - mu) * rinv * gg[nt] + bb[nt];
        v = fmaxf(v, 0.f);
        xs[orow][nt*16 + l15] = f2bf(v);   // wave-private rows: no barrier
      }
    }
  }

  // ================= GEMM2 + LN2 + SE partial sums =================
  {
    short8 a0 = *(const short8*)&xs[rowA][  0 + kofs];
    short8 a1 = *(const short8*)&xs[rowA][ 32 + kofs];
    short8 a2 = *(const short8*)&xs[rowA][ 64 + kofs];
    short8 a3 = *(const short8*)&xs[rowA][ 96 + kofs];

    f32x4 acc[8];
    #pragma unroll
    for (int nt = 0; nt < 8; nt++) {
      const unsigned short* wp = w2t + nt*2048 + lane8;
      short8 bv0 = *(const short8*)(wp);
      short8 bv1 = *(const short8*)(wp + 512);
      short8 bv2 = *(const short8*)(wp + 1024);
      short8 bv3 = *(const short8*)(wp + 1536);
      f32x4 c = {0.f,0.f,0.f,0.f};
      c = __builtin_amdgcn_mfma_f32_16x16x32_bf16(a0, bv0, c, 0, 0, 0);
      c = __builtin_amdgcn_mfma_f32_16x16x32_bf16(a1, bv1, c, 0, 0, 0);
      c = __builtin_amdgcn_mfma_f32_16x16x32_bf16(a2, bv2, c, 0, 0, 0);
      c = __builtin_amdgcn_mfma_f32_16x16x32_bf16(a3, bv3, c, 0, 0, 0);
      acc[nt] = c;
    }

    float gg[8], bb[8], ch[8];
    #pragma unroll
    for (int nt = 0; nt < 8; nt++) {
      gg[nt] = g2v[nt*16 + l15]; bb[nt] = b2v[nt*16 + l15]; ch[nt] = 0.f;
    }
    #pragma unroll
    for (int r = 0; r < 4; r++) {
      float s = 0.f, q = 0.f;
      #pragma unroll
      for (int nt = 0; nt < 8; nt++) { float v = acc[nt][r]; s += v; q += v*v; }
      #pragma unroll
      for (int m = 1; m < 16; m <<= 1) { s += __shfl_xor(s, m); q += __shfl_xor(q, m); }
      float mu = s * (1.f/128.f);
      float var = fmaxf(q * (1.f/128.f) - mu*mu, 0.f);
      float rinv = rsqrtf(var + 1e-5f);
      int orow = wbase + quad*4 + r;
      bool rv = (rowbase + orow) < nrows;
      #pragma unroll
      for (int nt = 0; nt < 8; nt++) {
        float v = (acc[nt][r] - mu) * rinv * gg[nt] + bb[nt];
        if (rv) ch[nt] += v;
        xs[orow][nt*16 + l15] = f2bf(v);
      }
    }
    // SE channel partials: reduce across quads, then LDS atomics
    #pragma unroll
    for (int nt = 0; nt < 8; nt++) {
      float v = ch[nt];
      v += __shfl_xor(v, 16); v += __shfl_xor(v, 32);
      if (quad == 0) atomicAdd(&sqs[nt*16 + l15], v);
    }
  }

  __syncthreads();
  // vector store y2: bf16, fully coalesced ushort8
  #pragma unroll
  for (int m = 0; m < 4; m++) {
    int c = m*256 + t;              // 1024 chunks of 8 shorts
    int row = c >> 4, s8 = c & 15;
    if (rowbase + row < nrows) {
      short8 v = *(const short8*)&xs[row][s8*8];
      *(short8*)(Y + (size_t)(rowbase+row)*128 + s8*8) = v;
    }
  }
  if (t < 128) atomicAdd(&sq[t], sqs[t]);
}

// ---------------- SE: mean -> fc -> relu -> fc -> sigmoid ----------------
__global__ void se_kernel(const float* __restrict__ sq, const float* __restrict__ w1,
    const float* __restrict__ b1, const float* __restrict__ w2,
    const float* __restrict__ b2, float* __restrict__ scale)
{
  __shared__ float mean[128];
  __shared__ float h1[32];
  int t = threadIdx.x; // 128 threads
  mean[t] = sq[t] * (1.f/(float)NVOX);
  __syncthreads();
  if(t < 32){
    float s = b1[t];
    for(int c=0;c<128;c++) s += mean[c]*w1[c*32+t];
    h1[t] = fmaxf(s, 0.f);
  }
  __syncthreads();
  float s = b2[t];
  for(int j=0;j<32;j++) s += h1[j]*w2[j*128+t];
  scale[t] = 1.f/(1.f + expf(-s));
}

// ---------------- scatter: accum[rank(lin)] += y2*scale + feats ----------------
__global__ void scatter_kernel(const unsigned short* __restrict__ y2,
    const float* __restrict__ feats, const float* __restrict__ scale,
    const int* __restrict__ lin, const unsigned long long* __restrict__ bits,
    const unsigned* __restrict__ coarse, const unsigned* __restrict__ blockExcl,
    float* __restrict__ accum)
{
  int row = blockIdx.x*4 + (threadIdx.x >> 6);
  int lane = threadIdx.x & 63;
  int l = lin[row];
  int w = l >> 6;
  unsigned j = coarse[w] + blockExcl[w >> 12]
             + (unsigned)__popcll(bits[w] & ((1ull << (l & 63)) - 1ull));
  size_t rb = (size_t)row * 128;
  float v0 = bf2f(y2[rb + lane])      * scale[lane]      + feats[rb + lane];
  float v1 = bf2f(y2[rb + 64 + lane]) * scale[64 + lane] + feats[rb + 64 + lane];
  size_t ob = (size_t)j * 128;
  atomicAdd(accum + ob + lane, v0);
  atomicAdd(accum + ob + 64 + lane, v1);
}

// ---------------- finalize: valid mask + relu, pad rows ----------------
__global__ void finalize_kernel(float* __restrict__ accum,
    const unsigned* __restrict__ blockExcl, float* __restrict__ out_comb,
    float* __restrict__ out_valid)
{
  int row = blockIdx.x*4 + (threadIdx.x >> 6);
  int lane = threadIdx.x & 63;
  unsigned U = blockExcl[128];
  size_t rb = (size_t)row * 128;
  if((unsigned)row < U){
    float v0 = accum[rb + lane], v1 = accum[rb + 64 + lane];
    float s = fabsf(v0) + fabsf(v1);
    #pragma unroll
    for(int m=1;m<64;m<<=1) s += __shfl_xor(s, m);
    bool valid = s > 1e-8f;
    accum[rb + lane]      = valid ? fmaxf(v0, 0.f) : 0.f;
    accum[rb + 64 + lane] = valid ? fmaxf(v1, 0.f) : 0.f;
    if(lane == 0) out_valid[row] = valid ? 1.f : 0.f;
  } else {
    accum[rb + lane] = 0.f;
    accum[rb + 64 + lane] = 0.f;
    if(lane == 0) out_valid[row] = 0.f;
    if(lane < 4) out_comb[(size_t)row*4 + lane] = (lane == 0) ? 8.f : 0.f;
  }
}

extern "C" void kernel_launch(void* const* d_in, const int* in_sizes, int n_in,
                              void* d_out, int out_size, void* d_ws, size_t ws_size,
                              hipStream_t stream)
{
  const float* feats   = (const float*)d_in[0];
  const int*   indices = (const int*)d_in[1];
  const float* W1  = (const float*)d_in[2];
  const float* g1  = (const float*)d_in[3];
  const float* b1  = (const float*)d_in[4];
  const float* W2  = (const float*)d_in[5];
  const float* g2  = (const float*)d_in[6];
  const float* b2  = (const float*)d_in[7];
  const float* sw1 = (const float*)d_in[8];
  const float* sb1 = (const float*)d_in[9];
  const float* sw2 = (const float*)d_in[10];
  const float* sb2 = (const float*)d_in[11];

  float* out_merged = (float*)d_out;                        // [2N,128]
  float* out_comb   = out_merged + (size_t)2*NVOX*128;      // [2N,4]
  float* out_valid  = out_comb   + (size_t)2*NVOX*4;        // [2N]

  char* cur = (char*)d_ws;
  auto alloc = [&](size_t b) -> void* {
    void* p = (void*)cur;
    cur += (b + 255) & ~(size_t)255;
    return p;
  };
  unsigned short*      y2        = (unsigned short*)alloc((size_t)NVOX*128*2);
  unsigned long long*  bits      = (unsigned long long*)alloc((size_t)NWORDS*8);
  unsigned*            coarse    = (unsigned*)alloc((size_t)NWORDS*4);
  unsigned*            blockSums = (unsigned*)alloc(128*4);
  unsigned*            blockExcl = (unsigned*)alloc(129*4);
  float*               sq        = (float*)alloc(128*4);
  float*               scale     = (float*)alloc(128*4);
  int*                 lin       = (int*)alloc((size_t)NVOX*4);
  unsigned short*      w1t       = (unsigned short*)alloc(128*128*2);
  unsigned short*      w2t       = (unsigned short*)alloc(128*128*2);

  hipMemsetAsync(bits, 0, (size_t)NWORDS*8, stream);
  hipMemsetAsync(sq, 0, 128*4, stream);
  hipMemsetAsync(out_merged, 0, (size_t)NVOX*128*4, stream); // accum rows < U <= N

  pack_w<<<64, 256, 0, stream>>>(W1, w1t);
  pack_w<<<64, 256, 0, stream>>>(W2, w2t);

  mark_kernel<<<(NVOX+255)/256, 256, 0, stream>>>(indices, bits, lin);
  scan1_kernel<<<128, 256, 0, stream>>>(bits, coarse, blockSums);
  scan2_kernel<<<1, 128, 0, stream>>>(blockSums, blockExcl);
  emit_kernel<<<NWORDS/256, 256, 0, stream>>>(bits, coarse, blockExcl, out_comb);

  fused_mlp<<<(NVOX+63)/64, 256, 0, stream>>>(feats, w1t, g1, b1, w2t, g2, b2,
                                              y2, sq, NVOX);
  se_kernel<<<1, 128, 0, stream>>>(sq, sw1, sb1, sw2, sb2, scale);

  scatter_kernel<<<NVOX/4, 256, 0, stream>>>(y2, feats, scale, lin, bits, coarse, blockExcl, out_merged);
  finalize_kernel<<<(2*NVOX)/4, 256, 0, stream>>>(out_merged, blockExcl, out_comb, out_valid);
}